// Round 7
// baseline (730.602 us; speedup 1.0000x reference)
//
#include <hip/hip_runtime.h>
#include <cmath>

namespace {
constexpr int B = 8;
constexpr int T = 2048;
constexpr int D = 512;
constexpr int S = 2048;
constexpr int R = 64;
constexpr int KTOP = 16;
constexpr int NT = 4;    // rows per block in topk kernels
constexpr int NR = 16;   // rows per block in qk kernel
constexpr int CAP = 256; // bin capacity per (b,slot); overflow -> atomic fallback

typedef __bf16 bf16x8 __attribute__((ext_vector_type(8)));
typedef float  f32x4  __attribute__((ext_vector_type(4)));

__device__ __forceinline__ float signf(float v) {
    return (v > 0.f) ? 1.f : ((v < 0.f) ? -1.f : 0.f);
}

__device__ __forceinline__ float bfhi(unsigned u) {   // high bf16 of a u32 pair
    return __uint_as_float(u & 0xffff0000u);
}
__device__ __forceinline__ float bflo(unsigned u) {   // low bf16
    return __uint_as_float(u << 16);
}

// Hybrid exact top-16 by |value| (ties -> lower index) over a row of S=2048.
// v[] holds bf16-approx values decoded to f32: v[i] comp c = row[4*(lane+64*i)+c].
// arow: 64 f32 in LDS (wave's A-row); bmat: [n][64] f32 — exact value of col j
// is dot(arow, bmat[j]). Candidates filtered by approx with margin, then
// recomputed exactly. Lane k (k<16) gets myg (exact signed value), myj.
__device__ __forceinline__ void topk16_hybrid(float4* v,
                                              const float* __restrict__ arow,
                                              const float* __restrict__ bmat,
                                              unsigned long long* __restrict__ cand,
                                              int lane, float& myg, int& myj) {
    // Phase 1: per-lane abs max of approx
    float lmax = 0.f;
#pragma unroll
    for (int i = 0; i < 8; i++) {
        lmax = fmaxf(lmax, fmaxf(fmaxf(fabsf(v[i].x), fabsf(v[i].y)),
                                 fmaxf(fabsf(v[i].z), fabsf(v[i].w))));
    }
    // Phase 2: bitonic sort (descending) of 64 lane maxes; t = 16th largest
    {
        float vv = lmax;
#pragma unroll
        for (int size = 2; size <= 64; size <<= 1) {
#pragma unroll
            for (int stride = size >> 1; stride > 0; stride >>= 1) {
                float o = __shfl_xor(vv, stride, 64);
                bool takeMax = ((lane & size) == 0) == ((lane & stride) == 0);
                vv = takeMax ? fmaxf(vv, o) : fminf(vv, o);
            }
        }
        lmax = __shfl(vv, 15);
    }
    // margin covers bf16-storage + bf16-MFMA approx error (stat bound ~24x rms)
    float thr = lmax - (lmax * 0.03125f + 1e-6f);
    // Phase 3: count candidates >= thr, prefix-sum
    int cnt = 0;
#pragma unroll
    for (int i = 0; i < 8; i++) {
        cnt += (fabsf(v[i].x) >= thr) + (fabsf(v[i].y) >= thr) +
               (fabsf(v[i].z) >= thr) + (fabsf(v[i].w) >= thr);
    }
    int off = cnt;
#pragma unroll
    for (int d = 1; d < 64; d <<= 1) {
        int o = __shfl_up(off, d, 64);
        if (lane >= d) off += o;
    }
    int total = __shfl(off, 63);
    int base = off - cnt;

    if (total <= 64) {
        // exact recompute of each candidate, pack (|exact|, -j, sign)
        int pos = base;
        const float4* ap = (const float4*)arow;
#pragma unroll
        for (int i = 0; i < 8; i++) {
            float c[4] = {v[i].x, v[i].y, v[i].z, v[i].w};
#pragma unroll
            for (int cc = 0; cc < 4; cc++) {
                if (fabsf(c[cc]) >= thr) {
                    int j = 4 * (lane + 64 * i) + cc;
                    const float4* bp = (const float4*)(bmat + (size_t)j * R);
                    float dot = 0.f;
#pragma unroll
                    for (int q2 = 0; q2 < 16; q2++) {
                        float4 bv = bp[q2];
                        float4 av = ap[q2];
                        dot += av.x * bv.x + av.y * bv.y + av.z * bv.z + av.w * bv.w;
                    }
                    unsigned bits = __float_as_uint(dot);
                    unsigned ab = bits & 0x7fffffffu;
                    unsigned sg = bits >> 31;
                    cand[pos++] = ((unsigned long long)ab << 12) |
                                  ((unsigned long long)(2047 - j) << 1) | sg;
                }
            }
        }
        unsigned long long key = (lane < total) ? cand[lane] : 0ull;
#pragma unroll
        for (int size = 2; size <= 64; size <<= 1) {
#pragma unroll
            for (int stride = size >> 1; stride > 0; stride >>= 1) {
                unsigned long long o =
                    (unsigned long long)__shfl_xor((long long)key, stride, 64);
                bool takeMax = ((lane & size) == 0) == ((lane & stride) == 0);
                key = (takeMax == (key > o)) ? key : o;
            }
        }
        myg = 0.f; myj = 0;
        if (lane < KTOP) {
            myj = 2047 - (int)((key >> 1) & 2047ull);
            unsigned ab = (unsigned)(key >> 12);
            unsigned sg = (unsigned)(key & 1ull);
            myg = __uint_as_float((sg << 31) | ab);
        }
    } else {
        // Fallback (rare): approx-based 16 rounds of argmax with removal
        myg = 0.f; myj = 0;
        for (int k = 0; k < KTOP; k++) {
            float bv = -1.f, bs = 0.f; int bj = 0;
#pragma unroll
            for (int i = 0; i < 8; i++) {
                int jb = 4 * (lane + 64 * i);
                { float a = fabsf(v[i].x); if (a > bv) { bv = a; bs = v[i].x; bj = jb; } }
                { float a = fabsf(v[i].y); if (a > bv) { bv = a; bs = v[i].y; bj = jb + 1; } }
                { float a = fabsf(v[i].z); if (a > bv) { bv = a; bs = v[i].z; bj = jb + 2; } }
                { float a = fabsf(v[i].w); if (a > bv) { bv = a; bs = v[i].w; bj = jb + 3; } }
            }
#pragma unroll
            for (int o2 = 32; o2 > 0; o2 >>= 1) {
                float ov = __shfl_xor(bv, o2, 64);
                float os = __shfl_xor(bs, o2, 64);
                int   oj = __shfl_xor(bj, o2, 64);
                if (ov > bv || (ov == bv && oj < bj)) { bv = ov; bs = os; bj = oj; }
            }
            if (lane == k) { myg = bs; myj = bj; }
            if (((bj >> 2) & 63) == lane) {
                int ii = bj >> 8, cc = bj & 3;
#pragma unroll
                for (int i2 = 0; i2 < 8; i2++) if (ii == i2) {
                    if (cc == 0) v[i2].x = 0.f; else if (cc == 1) v[i2].y = 0.f;
                    else if (cc == 2) v[i2].z = 0.f; else v[i2].w = 0.f;
                }
            }
        }
    }
}
} // namespace

// ---------- state init ----------
__global__ void k_init_state(const float* __restrict__ init_state,
                             float* __restrict__ state_ws) {
    int b = blockIdx.x;
    int tid = threadIdx.x;
    __shared__ float red[256];
    float m = -1e30f;
    for (int s = tid; s < S; s += 256) m = fmaxf(m, fabsf(init_state[s]));
    red[tid] = m; __syncthreads();
    for (int off = 128; off > 0; off >>= 1) {
        if (tid < off) red[tid] = fmaxf(red[tid], red[tid + off]);
        __syncthreads();
    }
    m = red[0]; __syncthreads();
    float sum = 0.f;
    for (int s = tid; s < S; s += 256) sum += expf(fabsf(init_state[s]) - m);
    red[tid] = sum; __syncthreads();
    for (int off = 128; off > 0; off >>= 1) {
        if (tid < off) red[tid] += red[tid + off];
        __syncthreads();
    }
    float inv = 1.0f / red[0];
    for (int s = tid; s < S; s += 256) {
        float v = init_state[s];
        state_ws[(size_t)b * S + s] = signf(v) * expf(fabsf(v) - m) * inv;
    }
}

// ---------- val broadcast init ----------
__global__ void k_bcast(const float* __restrict__ init_val,
                        float* __restrict__ val1) {
    int wv = threadIdx.x >> 6;
    int lane = threadIdx.x & 63;
    int row = blockIdx.x * 4 + wv;
    int s = row & (S - 1);
    const float4* src = (const float4*)(init_val + (size_t)s * D);
    float4 v0 = src[lane], v1 = src[lane + 64];
    float ss = v0.x * v0.x + v0.y * v0.y + v0.z * v0.z + v0.w * v0.w
             + v1.x * v1.x + v1.y * v1.y + v1.z * v1.z + v1.w * v1.w;
#pragma unroll
    for (int off = 32; off > 0; off >>= 1) ss += __shfl_xor(ss, off, 64);
    float sc = 1.0f / (sqrtf(ss) + 1e-6f);
    v0.x *= sc; v0.y *= sc; v0.z *= sc; v0.w *= sc;
    v1.x *= sc; v1.y *= sc; v1.z *= sc; v1.w *= sc;
    float4* dst = (float4*)(val1 + (size_t)row * D);
    dst[lane] = v0; dst[lane + 64] = v1;
}

// ---------- route_b transpose -> f32 + bf16 [S][R] ----------
__global__ void __launch_bounds__(256) k_prep(const float* __restrict__ rb,
                                              float* __restrict__ rbT_f32,
                                              __bf16* __restrict__ rbT_bf) {
    __shared__ float tile[64][65];
    int tid = threadIdx.x;
    int lane = tid & 63;
    int s0 = blockIdx.x * 64;
    for (int r = tid >> 6; r < 64; r += 4)
        tile[r][lane] = rb[(size_t)r * S + s0 + lane];
    __syncthreads();
    for (int idx = tid; idx < 4096; idx += 256) {
        int sl = idx >> 6, r = idx & 63;
        float v = tile[r][sl];
        rbT_f32[(size_t)(s0 + sl) * R + r] = v;
        rbT_bf[(size_t)(s0 + sl) * R + r] = (__bf16)v;
    }
}

// ---------- xr = x . route_a (f32 exact -> f32 + bf16), plus xinv ----------
__global__ void __launch_bounds__(256) k_xr(const float* __restrict__ x,
                                            const float* __restrict__ route_a,
                                            float* __restrict__ xr_f32,
                                            __bf16* __restrict__ xr_bf,
                                            float* __restrict__ xinv_g) {
    __shared__ __align__(16) float xs[NT][D];
    __shared__ float red[256];
    int tid = threadIdx.x;
    int lane = tid & 63, wv = tid >> 6;
    int tb = blockIdx.x * NT;
    {
        const float4* xg = (const float4*)(x + (size_t)tb * D);
        float4* xls = (float4*)&xs[0][0];
        xls[tid] = xg[tid];
        xls[tid + 256] = xg[tid + 256];
    }
    __syncthreads();
    {
        int r = lane, grp = wv;
        float acc[NT] = {0.f, 0.f, 0.f, 0.f};
        for (int d0 = grp * 128; d0 < grp * 128 + 128; d0 += 4) {
            float a0 = route_a[(size_t)(d0 + 0) * R + r];
            float a1 = route_a[(size_t)(d0 + 1) * R + r];
            float a2 = route_a[(size_t)(d0 + 2) * R + r];
            float a3 = route_a[(size_t)(d0 + 3) * R + r];
#pragma unroll
            for (int tt = 0; tt < NT; tt++) {
                float4 xv = *(const float4*)&xs[tt][d0];
                acc[tt] += xv.x * a0 + xv.y * a1 + xv.z * a2 + xv.w * a3;
            }
        }
        for (int tt = 0; tt < NT; tt++) {
            red[tid] = acc[tt]; __syncthreads();
            if (tid < 64) {
                float xrv = red[tid] + red[tid + 64] + red[tid + 128] + red[tid + 192];
                xr_f32[(size_t)(tb + tt) * R + tid] = xrv;
                xr_bf[(size_t)(tb + tt) * R + tid] = (__bf16)xrv;
            }
            __syncthreads();
        }
    }
    // per-wave xinv for token wv
    {
        const float4* xst = (const float4*)&xs[wv][0];
        float4 x0 = xst[lane], x1 = xst[lane + 64];
        float ss = x0.x * x0.x + x0.y * x0.y + x0.z * x0.z + x0.w * x0.w
                 + x1.x * x1.x + x1.y * x1.y + x1.z * x1.z + x1.w * x1.w;
#pragma unroll
        for (int off = 32; off > 0; off >>= 1) ss += __shfl_xor(ss, off, 64);
        if (lane == 0) xinv_g[tb + wv] = 1.0f / (sqrtf(ss) + 1e-6f);
    }
}

// ---------- scores = xr . route_b via bf16 MFMA; bf16 out [B*T][S] ----------
__global__ void __launch_bounds__(256) k_sgemm(const __bf16* __restrict__ xr_bf,
                                               const __bf16* __restrict__ rbT_bf,
                                               __bf16* __restrict__ scores_bf) {
    int lane = threadIdx.x & 63, wv = threadIdx.x >> 6;
    int mgrp = blockIdx.x >> 3;          // 64-row group (256 total)
    int nch  = blockIdx.x & 7;           // 256-col chunk
    int mbase = mgrp * 64 + wv * 16;
    int n0 = nch * 256;
    int quad = lane >> 4;
    int koff = quad << 3;
    const bf16x8* arow = (const bf16x8*)(xr_bf + (size_t)(mbase + (lane & 15)) * R + koff);
    bf16x8 a0 = arow[0], a1 = arow[4];
    int crow = mbase + (quad << 2);
#pragma unroll 4
    for (int nt = 0; nt < 16; nt++) {
        int ncol = n0 + nt * 16 + (lane & 15);
        const bf16x8* brow = (const bf16x8*)(rbT_bf + (size_t)ncol * R + koff);
        bf16x8 b0 = brow[0], b1 = brow[4];
        f32x4 c = {0.f, 0.f, 0.f, 0.f};
        c = __builtin_amdgcn_mfma_f32_16x16x32_bf16(a0, b0, c, 0, 0, 0);
        c = __builtin_amdgcn_mfma_f32_16x16x32_bf16(a1, b1, c, 0, 0, 0);
#pragma unroll
        for (int rg = 0; rg < 4; rg++)
            scores_bf[(size_t)(crow + rg) * S + ncol] = (__bf16)c[rg];
    }
}

// ---------- topk over bf16 score rows (exact recompute) -> bins/coef/state ----------
__global__ void __launch_bounds__(256) k_stopk(const __bf16* __restrict__ scores_bf,
                                               const float* __restrict__ xr_f32,
                                               const float* __restrict__ rbT_f32,
                                               const float* __restrict__ xinv_g,
                                               const float* __restrict__ x,
                                               float* __restrict__ val1,
                                               float* __restrict__ state_ws,
                                               float* __restrict__ coef,
                                               int* __restrict__ bincount,
                                               int* __restrict__ binlist) {
    __shared__ unsigned long long cand[NT][64];
    __shared__ float arow_s[NT][64];
    int lane = threadIdx.x & 63, wv = threadIdx.x >> 6;
    int tglob = blockIdx.x * NT + wv;
    int b = tglob >> 11;
    int tloc = tglob & (T - 1);

    arow_s[wv][lane] = xr_f32[(size_t)tglob * R + lane];

    float4 v[8];
    {
        const uint2* rp = (const uint2*)(scores_bf + (size_t)tglob * S);
#pragma unroll
        for (int i = 0; i < 8; i++) {
            uint2 u = rp[lane + 64 * i];
            v[i].x = bflo(u.x); v[i].y = bfhi(u.x);
            v[i].z = bflo(u.y); v[i].w = bfhi(u.y);
        }
    }
    float myg; int myj;
    topk16_hybrid(v, &arow_s[wv][0], rbT_f32, &cand[wv][0], lane, myg, myj);

    float m = __shfl(fabsf(myg), 0);
    float e = (lane < KTOP) ? expf(fabsf(myg) - m) : 0.f;
    float esum = e;
#pragma unroll
    for (int off = 8; off > 0; off >>= 1) esum += __shfl_xor(esum, off, 64);
    esum = __shfl(esum, 0);
    float w = signf(myg) * e / esum;
    float coefv = w * xinv_g[tglob];

    unsigned long long ovf = 0ull;
    int pos = 0;
    if (lane < KTOP) {
        float sp = (myg > 20.f) ? myg : log1pf(expf(myg));
        atomicAdd(&state_ws[(size_t)b * S + myj], sp);
        pos = atomicAdd(&bincount[(size_t)b * S + myj], 1);
        if (pos < CAP) {
            binlist[((size_t)b * S + myj) * CAP + pos] = (tloc << 4) | lane;
            coef[(size_t)tglob * KTOP + lane] = coefv;
        }
    }
    ovf = __ballot(lane < KTOP && pos >= CAP);
    while (ovf) {   // overflow fallback (essentially never)
        int src = __ffsll(ovf) - 1;
        int j = __shfl(myj, src);
        float c = __shfl(coefv, src);
        const float* xp = x + (size_t)tglob * D;
        float* dst = val1 + ((size_t)b * S + j) * D;
#pragma unroll
        for (int i = 0; i < 8; i++)
            atomicAdd(&dst[lane + 64 * i], c * xp[lane + 64 * i]);
        ovf &= ovf - 1;
    }
}

// ---------- accumulate bins (4-wide unrolled gather) ----------
__global__ void __launch_bounds__(256) k_accum(const float* __restrict__ x,
                                               const float* __restrict__ coef,
                                               const int* __restrict__ bincount,
                                               const int* __restrict__ binlist,
                                               float* __restrict__ val1) {
    int lane = threadIdx.x & 63, wv = threadIdx.x >> 6;
    int row = blockIdx.x * 4 + wv;
    int b = row >> 11;
    float4* vp4 = (float4*)(val1 + (size_t)row * D);
    float4 a0 = vp4[lane], a1 = vp4[lane + 64];
    int n = bincount[row]; if (n > CAP) n = CAP;
    const int* lp = binlist + (size_t)row * CAP;
    const float* xb = x + ((size_t)b * T) * D;
    for (int base = 0; base < n; base += 64) {
        int mm = n - base; if (mm > 64) mm = 64;
        int ent = 0; float cc = 0.f;
        if (lane < mm) {
            ent = lp[base + lane];
            cc = coef[((size_t)b * T + (ent >> 4)) * KTOP + (ent & 15)];
        }
        int mmr = (mm + 3) & ~3;
        for (int k = 0; k < mmr; k += 4) {
            int ea[4]; float ca[4];
#pragma unroll
            for (int u = 0; u < 4; u++) {
                ea[u] = __shfl(ent, k + u);
                ca[u] = __shfl(cc, k + u);
            }
            float4 v0[4], v1[4];
#pragma unroll
            for (int u = 0; u < 4; u++) {
                const float4* xp4 = (const float4*)(xb + (size_t)(ea[u] >> 4) * D);
                v0[u] = xp4[lane]; v1[u] = xp4[lane + 64];
            }
#pragma unroll
            for (int u = 0; u < 4; u++) {
                float c = ca[u];
                a0.x += c * v0[u].x; a0.y += c * v0[u].y;
                a0.z += c * v0[u].z; a0.w += c * v0[u].w;
                a1.x += c * v1[u].x; a1.y += c * v1[u].y;
                a1.z += c * v1[u].z; a1.w += c * v1[u].w;
            }
        }
    }
    float ss = a0.x * a0.x + a0.y * a0.y + a0.z * a0.z + a0.w * a0.w
             + a1.x * a1.x + a1.y * a1.y + a1.z * a1.z + a1.w * a1.w;
#pragma unroll
    for (int off = 32; off > 0; off >>= 1) ss += __shfl_xor(ss, off, 64);
    float sc = 1.0f / (sqrtf(ss) + 1e-6f);
    a0.x *= sc; a0.y *= sc; a0.z *= sc; a0.w *= sc;
    a1.x *= sc; a1.y *= sc; a1.z *= sc; a1.w *= sc;
    vp4[lane] = a0; vp4[lane + 64] = a1;
}

// ---------- state finalize ----------
__global__ void k_state_final(const float* __restrict__ state_ws,
                              float* __restrict__ out) {
    int b = blockIdx.x;
    int tid = threadIdx.x;
    __shared__ float red[256];
    const float* sp = state_ws + (size_t)b * S;
    float m = -1e30f;
    for (int s = tid; s < S; s += 256) m = fmaxf(m, fabsf(sp[s]));
    red[tid] = m; __syncthreads();
    for (int off = 128; off > 0; off >>= 1) {
        if (tid < off) red[tid] = fmaxf(red[tid], red[tid + off]);
        __syncthreads();
    }
    m = red[0]; __syncthreads();
    float sum = 0.f;
    for (int s = tid; s < S; s += 256) sum += expf(fabsf(sp[s]) - m);
    red[tid] = sum; __syncthreads();
    for (int off = 128; off > 0; off >>= 1) {
        if (tid < off) red[tid] += red[tid + off];
        __syncthreads();
    }
    float inv = 1.0f / red[0];
    for (int s = tid; s < S; s += 256) {
        float v = sp[s];
        out[((size_t)b * S + s) * (D + 1)] = signf(v) * expf(fabsf(v) - m) * inv;
    }
}

// ---------- q / k projections -> f32 + bf16 rows [B*S][R] ----------
__global__ void __launch_bounds__(256) k_qk2(const float* __restrict__ val1,
                                             const float* __restrict__ pair_a,
                                             const float* __restrict__ pair_b,
                                             float* __restrict__ q_f32,
                                             float* __restrict__ k_f32,
                                             __bf16* __restrict__ q_bf,
                                             __bf16* __restrict__ k_bf) {
    __shared__ __align__(16) float vrow[NR][D];
    __shared__ float redq[256];
    __shared__ float redk[256];
    int tid = threadIdx.x;
    int rowbase = blockIdx.x * NR;
    {
        const float4* gv = (const float4*)(val1 + (size_t)rowbase * D);
        float4* lv = (float4*)&vrow[0][0];
        for (int i = tid; i < NR * D / 4; i += 256) lv[i] = gv[i];
    }
    __syncthreads();
    int r = tid & 63, grp = tid >> 6;
    float accq[NR], acck[NR];
#pragma unroll
    for (int rr = 0; rr < NR; rr++) { accq[rr] = 0.f; acck[rr] = 0.f; }
    for (int d0 = grp * 128; d0 < grp * 128 + 128; d0 += 4) {
#pragma unroll
        for (int dd = 0; dd < 4; dd++) {
            float a  = pair_a[(size_t)(d0 + dd) * R + r];
            float bb = pair_b[(size_t)(d0 + dd) * R + r];
#pragma unroll
            for (int rr = 0; rr < NR; rr++) {
                float v = vrow[rr][d0 + dd];
                accq[rr] += v * a;
                acck[rr] += v * bb;
            }
        }
    }
    for (int rr = 0; rr < NR; rr++) {
        redq[tid] = accq[rr]; redk[tid] = acck[rr];
        __syncthreads();
        if (tid < 64) {
            float qv = redq[tid] + redq[tid + 64] + redq[tid + 128] + redq[tid + 192];
            float kv = redk[tid] + redk[tid + 64] + redk[tid + 128] + redk[tid + 192];
            size_t o = (size_t)(rowbase + rr) * R + tid;
            q_f32[o] = qv; k_f32[o] = kv;
            q_bf[o] = (__bf16)qv; k_bf[o] = (__bf16)kv;
        }
        __syncthreads();
    }
}

// ---------- p = q . k^T via bf16 MFMA; bf16 out [B*S][S] ----------
__global__ void __launch_bounds__(256) k_pgemm(const __bf16* __restrict__ q_bf,
                                               const __bf16* __restrict__ k_bf,
                                               __bf16* __restrict__ p_bf) {
    int lane = threadIdx.x & 63, wv = threadIdx.x >> 6;
    int mgrp = blockIdx.x >> 3;
    int nch  = blockIdx.x & 7;
    int mbase = mgrp * 64 + wv * 16;     // global row in B*S
    int b = mbase >> 11;
    int n0 = nch * 256;
    int quad = lane >> 4;
    int koff = quad << 3;
    const bf16x8* arow = (const bf16x8*)(q_bf + (size_t)(mbase + (lane & 15)) * R + koff);
    bf16x8 a0 = arow[0], a1 = arow[4];
    int crow = mbase + (quad << 2);
    const __bf16* kb = k_bf + ((size_t)b << 11) * R;
#pragma unroll 4
    for (int nt = 0; nt < 16; nt++) {
        int ncol = n0 + nt * 16 + (lane & 15);
        const bf16x8* brow = (const bf16x8*)(kb + (size_t)ncol * R + koff);
        bf16x8 b0 = brow[0], b1 = brow[4];
        f32x4 c = {0.f, 0.f, 0.f, 0.f};
        c = __builtin_amdgcn_mfma_f32_16x16x32_bf16(a0, b0, c, 0, 0, 0);
        c = __builtin_amdgcn_mfma_f32_16x16x32_bf16(a1, b1, c, 0, 0, 0);
#pragma unroll
        for (int rg = 0; rg < 4; rg++)
            p_bf[(size_t)(crow + rg) * S + ncol] = (__bf16)c[rg];
    }
}

// ---------- topk over bf16 p rows (exact recompute) -> eidx/ew ----------
__global__ void __launch_bounds__(256) k_ptopk(const __bf16* __restrict__ p_bf,
                                               const float* __restrict__ q_f32,
                                               const float* __restrict__ k_f32,
                                               int* __restrict__ eidx,
                                               float* __restrict__ ew_g) {
    __shared__ unsigned long long cand[NT][64];
    __shared__ float arow_s[NT][64];
    int lane = threadIdx.x & 63, wv = threadIdx.x >> 6;
    int row = blockIdx.x * NT + wv;
    int b = row >> 11;

    arow_s[wv][lane] = q_f32[(size_t)row * R + lane];

    float4 v[8];
    {
        const uint2* rp = (const uint2*)(p_bf + (size_t)row * S);
#pragma unroll
        for (int i = 0; i < 8; i++) {
            uint2 u = rp[lane + 64 * i];
            v[i].x = bflo(u.x); v[i].y = bfhi(u.x);
            v[i].z = bflo(u.y); v[i].w = bfhi(u.y);
        }
    }
    float myg; int myj;
    topk16_hybrid(v, &arow_s[wv][0], k_f32 + (((size_t)b << 11) * R),
                  &cand[wv][0], lane, myg, myj);

    float m = __shfl(fabsf(myg), 0);
    float e = (lane < KTOP) ? expf(fabsf(myg) - m) : 0.f;
    float esum = e;
#pragma unroll
    for (int off = 8; off > 0; off >>= 1) esum += __shfl_xor(esum, off, 64);
    esum = __shfl(esum, 0);
    float myw = signf(myg) * e / esum;

    if (lane < KTOP) {
        eidx[(size_t)row * KTOP + lane] = myj;
        ew_g[(size_t)row * KTOP + lane] = myw;
    }
}

// ---------- mix: gather neighbors, residual add, unit-norm, out[...,1:] ----------
__global__ void __launch_bounds__(256) k_mix(const int* __restrict__ eidx,
                                             const float* __restrict__ ew_g,
                                             const float* __restrict__ val1,
                                             float* __restrict__ out) {
    int lane = threadIdx.x & 63, wv = threadIdx.x >> 6;
    int row = blockIdx.x * 4 + wv;
    int b = row >> 11;

    int e_i = 0; float e_w = 0.f;
    if (lane < KTOP) {
        e_i = eidx[(size_t)row * KTOP + lane];
        e_w = ew_g[(size_t)row * KTOP + lane];
    }

    const float4* self4 = (const float4*)(val1 + (size_t)row * D);
    float4 a0 = self4[lane], a1 = self4[lane + 64];
#pragma unroll
    for (int k = 0; k < KTOP; k++) {
        int j = __shfl(e_i, k);
        float w = __shfl(e_w, k);
        const float4* nb4 = (const float4*)(val1 + ((size_t)b * S + j) * D);
        float4 v0 = nb4[lane], v1 = nb4[lane + 64];
        a0.x += w * v0.x; a0.y += w * v0.y; a0.z += w * v0.z; a0.w += w * v0.w;
        a1.x += w * v1.x; a1.y += w * v1.y; a1.z += w * v1.z; a1.w += w * v1.w;
    }
    float ss = a0.x * a0.x + a0.y * a0.y + a0.z * a0.z + a0.w * a0.w
             + a1.x * a1.x + a1.y * a1.y + a1.z * a1.z + a1.w * a1.w;
#pragma unroll
    for (int off = 32; off > 0; off >>= 1) ss += __shfl_xor(ss, off, 64);
    float sc = 1.0f / (sqrtf(ss) + 1e-6f);
    float* op = out + (size_t)row * (D + 1) + 1;
    int d0 = 4 * lane;
    op[d0 + 0] = a0.x * sc; op[d0 + 1] = a0.y * sc;
    op[d0 + 2] = a0.z * sc; op[d0 + 3] = a0.w * sc;
    op[256 + d0 + 0] = a1.x * sc; op[256 + d0 + 1] = a1.y * sc;
    op[256 + d0 + 2] = a1.z * sc; op[256 + d0 + 3] = a1.w * sc;
}

extern "C" void kernel_launch(void* const* d_in, const int* in_sizes, int n_in,
                              void* d_out, int out_size, void* d_ws, size_t ws_size,
                              hipStream_t stream) {
    (void)in_sizes; (void)n_in; (void)out_size; (void)ws_size;
    const float* x          = (const float*)d_in[0];
    const float* init_state = (const float*)d_in[1];
    const float* init_val   = (const float*)d_in[2];
    const float* route_a    = (const float*)d_in[3];
    const float* route_b    = (const float*)d_in[4];
    const float* pair_a     = (const float*)d_in[5];
    const float* pair_b     = (const float*)d_in[6];
    float* out = (float*)d_out;

    float* ws       = (float*)d_ws;
    float* val1     = ws;                               // B*S*D f32
    float* state_ws = val1 + (size_t)B * S * D;         // B*S
    float* coef     = state_ws + (size_t)B * S;         // B*T*K
    float* xinv_g   = coef + (size_t)B * T * KTOP;      // B*T
    float* xr_f32   = xinv_g + (size_t)B * T;           // B*T*R
    float* rbT_f32  = xr_f32 + (size_t)B * T * R;       // S*R
    float* q_f32    = rbT_f32 + (size_t)S * R;          // B*S*R
    float* k_f32    = q_f32 + (size_t)B * S * R;        // B*S*R
    int*   bincount = (int*)(k_f32 + (size_t)B * S * R);// B*S
    int*   binlist  = bincount + (size_t)B * S;         // B*S*CAP
    int*   eidx     = binlist;                          // reuse (dead after accum)
    float* ew       = (float*)(binlist + (size_t)B * S * KTOP);
    __bf16* scores_bf = (__bf16*)(binlist + (size_t)B * S * CAP); // B*T*S (reused as p)
    __bf16* xr_bf   = scores_bf + (size_t)B * T * S;    // B*T*R
    __bf16* rbT_bf  = xr_bf + (size_t)B * T * R;        // S*R
    __bf16* q_bf    = rbT_bf + (size_t)S * R;           // B*S*R
    __bf16* k_bf    = q_bf + (size_t)B * S * R;         // B*S*R

    hipMemsetAsync(bincount, 0, (size_t)B * S * sizeof(int), stream);
    hipLaunchKernelGGL(k_init_state, dim3(B), dim3(256), 0, stream, init_state, state_ws);
    hipLaunchKernelGGL(k_bcast, dim3(B * S / 4), dim3(256), 0, stream, init_val, val1);
    hipLaunchKernelGGL(k_prep, dim3(S / 64), dim3(256), 0, stream, route_b, rbT_f32, rbT_bf);
    hipLaunchKernelGGL(k_xr, dim3(B * T / NT), dim3(256), 0, stream,
                       x, route_a, xr_f32, xr_bf, xinv_g);
    hipLaunchKernelGGL(k_sgemm, dim3(B * T / 64 * 8), dim3(256), 0, stream,
                       xr_bf, rbT_bf, scores_bf);
    hipLaunchKernelGGL(k_stopk, dim3(B * T / NT), dim3(256), 0, stream,
                       scores_bf, xr_f32, rbT_f32, xinv_g, x, val1, state_ws,
                       coef, bincount, binlist);
    hipLaunchKernelGGL(k_state_final, dim3(B), dim3(256), 0, stream, state_ws, out);
    hipLaunchKernelGGL(k_accum, dim3(B * S / 4), dim3(256), 0, stream,
                       x, coef, bincount, binlist, val1);
    hipLaunchKernelGGL(k_qk2, dim3(B * S / NR), dim3(256), 0, stream,
                       val1, pair_a, pair_b, q_f32, k_f32, q_bf, k_bf);
    hipLaunchKernelGGL(k_pgemm, dim3(B * S / 64 * 8), dim3(256), 0, stream,
                       q_bf, k_bf, scores_bf);
    hipLaunchKernelGGL(k_ptopk, dim3(B * S / NT), dim3(256), 0, stream,
                       scores_bf, q_f32, k_f32, eidx, ew);
    hipLaunchKernelGGL(k_mix, dim3(B * S / 4), dim3(256), 0, stream,
                       eidx, ew, val1, out);
}

// Round 9
// 533.688 us; speedup vs baseline: 1.3690x; 1.3690x over previous
//
#include <hip/hip_runtime.h>
#include <cmath>

namespace {
constexpr int B = 8;
constexpr int T = 2048;
constexpr int D = 512;
constexpr int S = 2048;
constexpr int R = 64;
constexpr int KTOP = 16;
constexpr int NT = 4;    // rows per block in xr kernel
constexpr int NR = 16;   // rows per block in qk kernel
constexpr int CAP = 256; // bin capacity per (b,slot); overflow -> atomic fallback

typedef __bf16 bf16x8 __attribute__((ext_vector_type(8)));
typedef float  f32x4  __attribute__((ext_vector_type(4)));

__device__ __forceinline__ float signf(float v) {
    return (v > 0.f) ? 1.f : ((v < 0.f) ? -1.f : 0.f);
}

// Exact top-16 by |value| (ties -> lower index) over a row of S=2048 floats in
// registers: v[i] comp c = row[4*(lane+64*i)+c]. Lane k (k<16) gets myg/myj in
// descending (|v|, -j) order.
__device__ __forceinline__ void topk16_reg(float4* v,
                                           unsigned long long* __restrict__ cand,
                                           int lane, float& myg, int& myj) {
    float lmax = 0.f;
#pragma unroll
    for (int i = 0; i < 8; i++) {
        lmax = fmaxf(lmax, fmaxf(fmaxf(fabsf(v[i].x), fabsf(v[i].y)),
                                 fmaxf(fabsf(v[i].z), fabsf(v[i].w))));
    }
    {
        float vv = lmax;
#pragma unroll
        for (int size = 2; size <= 64; size <<= 1) {
#pragma unroll
            for (int stride = size >> 1; stride > 0; stride >>= 1) {
                float o = __shfl_xor(vv, stride, 64);
                bool takeMax = ((lane & size) == 0) == ((lane & stride) == 0);
                vv = takeMax ? fmaxf(vv, o) : fminf(vv, o);
            }
        }
        lmax = __shfl(vv, 15);
    }
    float t = lmax;
    int cnt = 0;
#pragma unroll
    for (int i = 0; i < 8; i++) {
        cnt += (fabsf(v[i].x) >= t) + (fabsf(v[i].y) >= t) +
               (fabsf(v[i].z) >= t) + (fabsf(v[i].w) >= t);
    }
    int off = cnt;
#pragma unroll
    for (int d = 1; d < 64; d <<= 1) {
        int o = __shfl_up(off, d, 64);
        if (lane >= d) off += o;
    }
    int total = __shfl(off, 63);
    int base = off - cnt;

    if (total <= 64) {
        int pos = base;
#pragma unroll
        for (int i = 0; i < 8; i++) {
            float c[4] = {v[i].x, v[i].y, v[i].z, v[i].w};
#pragma unroll
            for (int cc = 0; cc < 4; cc++) {
                if (fabsf(c[cc]) >= t) {
                    unsigned bits = __float_as_uint(c[cc]);
                    unsigned ab = bits & 0x7fffffffu;
                    unsigned sg = bits >> 31;
                    int j = 4 * (lane + 64 * i) + cc;
                    cand[pos++] = ((unsigned long long)ab << 12) |
                                  ((unsigned long long)(2047 - j) << 1) | sg;
                }
            }
        }
        unsigned long long key = (lane < total) ? cand[lane] : 0ull;
#pragma unroll
        for (int size = 2; size <= 64; size <<= 1) {
#pragma unroll
            for (int stride = size >> 1; stride > 0; stride >>= 1) {
                unsigned long long o =
                    (unsigned long long)__shfl_xor((long long)key, stride, 64);
                bool takeMax = ((lane & size) == 0) == ((lane & stride) == 0);
                key = (takeMax == (key > o)) ? key : o;
            }
        }
        myg = 0.f; myj = 0;
        if (lane < KTOP) {
            myj = 2047 - (int)((key >> 1) & 2047ull);
            unsigned ab = (unsigned)(key >> 12);
            unsigned sg = (unsigned)(key & 1ull);
            myg = __uint_as_float((sg << 31) | ab);
        }
    } else {
        myg = 0.f; myj = 0;
        for (int k = 0; k < KTOP; k++) {
            float bv = -1.f, bs = 0.f; int bj = 0;
#pragma unroll
            for (int i = 0; i < 8; i++) {
                int jb = 4 * (lane + 64 * i);
                { float a = fabsf(v[i].x); if (a > bv) { bv = a; bs = v[i].x; bj = jb; } }
                { float a = fabsf(v[i].y); if (a > bv) { bv = a; bs = v[i].y; bj = jb + 1; } }
                { float a = fabsf(v[i].z); if (a > bv) { bv = a; bs = v[i].z; bj = jb + 2; } }
                { float a = fabsf(v[i].w); if (a > bv) { bv = a; bs = v[i].w; bj = jb + 3; } }
            }
#pragma unroll
            for (int o2 = 32; o2 > 0; o2 >>= 1) {
                float ov = __shfl_xor(bv, o2, 64);
                float os = __shfl_xor(bs, o2, 64);
                int   oj = __shfl_xor(bj, o2, 64);
                if (ov > bv || (ov == bv && oj < bj)) { bv = ov; bs = os; bj = oj; }
            }
            if (lane == k) { myg = bs; myj = bj; }
            if (((bj >> 2) & 63) == lane) {
                int ii = bj >> 8, cc = bj & 3;
#pragma unroll
                for (int i2 = 0; i2 < 8; i2++) if (ii == i2) {
                    if (cc == 0) v[i2].x = 0.f; else if (cc == 1) v[i2].y = 0.f;
                    else if (cc == 2) v[i2].z = 0.f; else v[i2].w = 0.f;
                }
            }
        }
    }
}
} // namespace

// ---------- state init ----------
__global__ void k_init_state(const float* __restrict__ init_state,
                             float* __restrict__ state_ws) {
    int b = blockIdx.x;
    int tid = threadIdx.x;
    __shared__ float red[256];
    float m = -1e30f;
    for (int s = tid; s < S; s += 256) m = fmaxf(m, fabsf(init_state[s]));
    red[tid] = m; __syncthreads();
    for (int off = 128; off > 0; off >>= 1) {
        if (tid < off) red[tid] = fmaxf(red[tid], red[tid + off]);
        __syncthreads();
    }
    m = red[0]; __syncthreads();
    float sum = 0.f;
    for (int s = tid; s < S; s += 256) sum += expf(fabsf(init_state[s]) - m);
    red[tid] = sum; __syncthreads();
    for (int off = 128; off > 0; off >>= 1) {
        if (tid < off) red[tid] += red[tid + off];
        __syncthreads();
    }
    float inv = 1.0f / red[0];
    for (int s = tid; s < S; s += 256) {
        float v = init_state[s];
        state_ws[(size_t)b * S + s] = signf(v) * expf(fabsf(v) - m) * inv;
    }
}

// ---------- val broadcast init ----------
__global__ void k_bcast(const float* __restrict__ init_val,
                        float* __restrict__ val1) {
    int wv = threadIdx.x >> 6;
    int lane = threadIdx.x & 63;
    int row = blockIdx.x * 4 + wv;
    int s = row & (S - 1);
    const float4* src = (const float4*)(init_val + (size_t)s * D);
    float4 v0 = src[lane], v1 = src[lane + 64];
    float ss = v0.x * v0.x + v0.y * v0.y + v0.z * v0.z + v0.w * v0.w
             + v1.x * v1.x + v1.y * v1.y + v1.z * v1.z + v1.w * v1.w;
#pragma unroll
    for (int off = 32; off > 0; off >>= 1) ss += __shfl_xor(ss, off, 64);
    float sc = 1.0f / (sqrtf(ss) + 1e-6f);
    v0.x *= sc; v0.y *= sc; v0.z *= sc; v0.w *= sc;
    v1.x *= sc; v1.y *= sc; v1.z *= sc; v1.w *= sc;
    float4* dst = (float4*)(val1 + (size_t)row * D);
    dst[lane] = v0; dst[lane + 64] = v1;
}

// ---------- route_b transpose -> bf16 hi/lo [S][R] ----------
__global__ void __launch_bounds__(256) k_prep(const float* __restrict__ rb,
                                              __bf16* __restrict__ rbT_hi,
                                              __bf16* __restrict__ rbT_lo) {
    __shared__ float tile[64][65];
    int tid = threadIdx.x;
    int lane = tid & 63;
    int s0 = blockIdx.x * 64;
    for (int r = tid >> 6; r < 64; r += 4)
        tile[r][lane] = rb[(size_t)r * S + s0 + lane];
    __syncthreads();
    for (int idx = tid; idx < 4096; idx += 256) {
        int sl = idx >> 6, r = idx & 63;
        float v = tile[r][sl];
        __bf16 h = (__bf16)v;
        rbT_hi[(size_t)(s0 + sl) * R + r] = h;
        rbT_lo[(size_t)(s0 + sl) * R + r] = (__bf16)(v - (float)h);
    }
}

// ---------- xr = x . route_a (f32 exact -> bf16 hi/lo), plus xinv ----------
__global__ void __launch_bounds__(256) k_xr(const float* __restrict__ x,
                                            const float* __restrict__ route_a,
                                            __bf16* __restrict__ xr_hi,
                                            __bf16* __restrict__ xr_lo,
                                            float* __restrict__ xinv_g) {
    __shared__ __align__(16) float xs[NT][D];
    __shared__ float red[256];
    int tid = threadIdx.x;
    int lane = tid & 63, wv = tid >> 6;
    int tb = blockIdx.x * NT;
    {
        const float4* xg = (const float4*)(x + (size_t)tb * D);
        float4* xls = (float4*)&xs[0][0];
        xls[tid] = xg[tid];
        xls[tid + 256] = xg[tid + 256];
    }
    __syncthreads();
    {
        int r = lane, grp = wv;
        float acc[NT] = {0.f, 0.f, 0.f, 0.f};
        for (int d0 = grp * 128; d0 < grp * 128 + 128; d0 += 4) {
            float a0 = route_a[(size_t)(d0 + 0) * R + r];
            float a1 = route_a[(size_t)(d0 + 1) * R + r];
            float a2 = route_a[(size_t)(d0 + 2) * R + r];
            float a3 = route_a[(size_t)(d0 + 3) * R + r];
#pragma unroll
            for (int tt = 0; tt < NT; tt++) {
                float4 xv = *(const float4*)&xs[tt][d0];
                acc[tt] += xv.x * a0 + xv.y * a1 + xv.z * a2 + xv.w * a3;
            }
        }
        for (int tt = 0; tt < NT; tt++) {
            red[tid] = acc[tt]; __syncthreads();
            if (tid < 64) {
                float xrv = red[tid] + red[tid + 64] + red[tid + 128] + red[tid + 192];
                __bf16 h = (__bf16)xrv;
                xr_hi[(size_t)(tb + tt) * R + tid] = h;
                xr_lo[(size_t)(tb + tt) * R + tid] = (__bf16)(xrv - (float)h);
            }
            __syncthreads();
        }
    }
    {
        const float4* xst = (const float4*)&xs[wv][0];
        float4 x0 = xst[lane], x1 = xst[lane + 64];
        float ss = x0.x * x0.x + x0.y * x0.y + x0.z * x0.z + x0.w * x0.w
                 + x1.x * x1.x + x1.y * x1.y + x1.z * x1.z + x1.w * x1.w;
#pragma unroll
        for (int off = 32; off > 0; off >>= 1) ss += __shfl_xor(ss, off, 64);
        if (lane == 0) xinv_g[tb + wv] = 1.0f / (sqrtf(ss) + 1e-6f);
    }
}

// ---------- fused: scores via split-bf16 MFMA -> f32 LDS halves -> topk ----------
__global__ void __launch_bounds__(256) k_score2(const __bf16* __restrict__ xr_hi,
                                                const __bf16* __restrict__ xr_lo,
                                                const __bf16* __restrict__ rbT_hi,
                                                const __bf16* __restrict__ rbT_lo,
                                                const float* __restrict__ xinv_g,
                                                const float* __restrict__ x,
                                                float* __restrict__ val1,
                                                float* __restrict__ state_ws,
                                                float* __restrict__ coef,
                                                int* __restrict__ bincount,
                                                int* __restrict__ binlist) {
    __shared__ __align__(16) float sc[16 * 1024];   // 64 KB: 16 rows x 1024-col half
    unsigned long long* candb = (unsigned long long*)sc;  // aliased after consumption

    int lane = threadIdx.x & 63, wv = threadIdx.x >> 6;
    int mbase = blockIdx.x * 16;
    int quad = lane >> 4, koff = quad << 3;
    size_t aoff = (size_t)(mbase + (lane & 15)) * R + koff;
    const bf16x8* ah = (const bf16x8*)(xr_hi + aoff);
    const bf16x8* al = (const bf16x8*)(xr_lo + aoff);
    bf16x8 a0h = ah[0], a1h = ah[4];
    bf16x8 a0l = al[0], a1l = al[4];
    int rl = quad << 2;
    int swz = quad << 3;               // f32-index XOR swizzle (bank spread)

    float4 v4[4][8];
    for (int half = 0; half < 2; half++) {
        for (int nt = 0; nt < 16; nt++) {
            int ncol = half * 1024 + wv * 256 + nt * 16 + (lane & 15);
            size_t boff = (size_t)ncol * R + koff;
            const bf16x8* bh = (const bf16x8*)(rbT_hi + boff);
            const bf16x8* bl = (const bf16x8*)(rbT_lo + boff);
            bf16x8 b0h = bh[0], b1h = bh[4];
            bf16x8 b0l = bl[0], b1l = bl[4];
            f32x4 c = {0.f, 0.f, 0.f, 0.f};
            c = __builtin_amdgcn_mfma_f32_16x16x32_bf16(a0h, b0h, c, 0, 0, 0);
            c = __builtin_amdgcn_mfma_f32_16x16x32_bf16(a1h, b1h, c, 0, 0, 0);
            c = __builtin_amdgcn_mfma_f32_16x16x32_bf16(a0h, b0l, c, 0, 0, 0);
            c = __builtin_amdgcn_mfma_f32_16x16x32_bf16(a1h, b1l, c, 0, 0, 0);
            c = __builtin_amdgcn_mfma_f32_16x16x32_bf16(a0l, b0h, c, 0, 0, 0);
            c = __builtin_amdgcn_mfma_f32_16x16x32_bf16(a1l, b1h, c, 0, 0, 0);
            int lcol = (ncol - half * 1024) ^ swz;
#pragma unroll
            for (int rg = 0; rg < 4; rg++)
                sc[(rl + rg) * 1024 + lcol] = c[rg];
        }
        __syncthreads();
        // each wave copies its 4 rows' half into registers (swizzle mirrored)
#pragma unroll
        for (int rr = 0; rr < 4; rr++) {
            const float4* rp = (const float4*)(sc + (wv * 4 + rr) * 1024);
#pragma unroll
            for (int i = 0; i < 4; i++)
                v4[rr][half * 4 + i] = rp[(lane + 64 * i) ^ (wv << 1)];
        }
        __syncthreads();
    }

    for (int rr = 0; rr < 4; rr++) {
        int tglob = mbase + wv * 4 + rr;
        int b = tglob >> 11;
        int tloc = tglob & (T - 1);
        float myg; int myj;
        topk16_reg(v4[rr], candb + wv * 64, lane, myg, myj);

        float m = __shfl(fabsf(myg), 0);
        float e = (lane < KTOP) ? expf(fabsf(myg) - m) : 0.f;
        float esum = e;
#pragma unroll
        for (int off = 8; off > 0; off >>= 1) esum += __shfl_xor(esum, off, 64);
        esum = __shfl(esum, 0);
        float w = signf(myg) * e / esum;
        float coefv = w * xinv_g[tglob];

        unsigned long long ovf = 0ull;
        int pos = 0;
        if (lane < KTOP) {
            float sp = (myg > 20.f) ? myg : log1pf(expf(myg));
            atomicAdd(&state_ws[(size_t)b * S + myj], sp);
            pos = atomicAdd(&bincount[(size_t)b * S + myj], 1);
            if (pos < CAP) {
                binlist[((size_t)b * S + myj) * CAP + pos] = (tloc << 4) | lane;
                coef[(size_t)tglob * KTOP + lane] = coefv;
            }
        }
        ovf = __ballot(lane < KTOP && pos >= CAP);
        while (ovf) {   // overflow fallback (essentially never)
            int src = __ffsll(ovf) - 1;
            int j = __shfl(myj, src);
            float c = __shfl(coefv, src);
            const float* xp = x + (size_t)tglob * D;
            float* dst = val1 + ((size_t)b * S + j) * D;
#pragma unroll
            for (int i = 0; i < 8; i++)
                atomicAdd(&dst[lane + 64 * i], c * xp[lane + 64 * i]);
            ovf &= ovf - 1;
        }
    }
}

// ---------- accumulate bins (4-wide unrolled gather) ----------
__global__ void __launch_bounds__(256) k_accum(const float* __restrict__ x,
                                               const float* __restrict__ coef,
                                               const int* __restrict__ bincount,
                                               const int* __restrict__ binlist,
                                               float* __restrict__ val1) {
    int lane = threadIdx.x & 63, wv = threadIdx.x >> 6;
    int row = blockIdx.x * 4 + wv;
    int b = row >> 11;
    float4* vp4 = (float4*)(val1 + (size_t)row * D);
    float4 a0 = vp4[lane], a1 = vp4[lane + 64];
    int n = bincount[row]; if (n > CAP) n = CAP;
    const int* lp = binlist + (size_t)row * CAP;
    const float* xb = x + ((size_t)b * T) * D;
    for (int base = 0; base < n; base += 64) {
        int mm = n - base; if (mm > 64) mm = 64;
        int ent = 0; float cc = 0.f;
        if (lane < mm) {
            ent = lp[base + lane];
            cc = coef[((size_t)b * T + (ent >> 4)) * KTOP + (ent & 15)];
        }
        int mmr = (mm + 3) & ~3;
        for (int k = 0; k < mmr; k += 4) {
            int ea[4]; float ca[4];
#pragma unroll
            for (int u = 0; u < 4; u++) {
                ea[u] = __shfl(ent, k + u);
                ca[u] = __shfl(cc, k + u);
            }
            float4 v0[4], v1[4];
#pragma unroll
            for (int u = 0; u < 4; u++) {
                const float4* xp4 = (const float4*)(xb + (size_t)(ea[u] >> 4) * D);
                v0[u] = xp4[lane]; v1[u] = xp4[lane + 64];
            }
#pragma unroll
            for (int u = 0; u < 4; u++) {
                float c = ca[u];
                a0.x += c * v0[u].x; a0.y += c * v0[u].y;
                a0.z += c * v0[u].z; a0.w += c * v0[u].w;
                a1.x += c * v1[u].x; a1.y += c * v1[u].y;
                a1.z += c * v1[u].z; a1.w += c * v1[u].w;
            }
        }
    }
    float ss = a0.x * a0.x + a0.y * a0.y + a0.z * a0.z + a0.w * a0.w
             + a1.x * a1.x + a1.y * a1.y + a1.z * a1.z + a1.w * a1.w;
#pragma unroll
    for (int off = 32; off > 0; off >>= 1) ss += __shfl_xor(ss, off, 64);
    float sc = 1.0f / (sqrtf(ss) + 1e-6f);
    a0.x *= sc; a0.y *= sc; a0.z *= sc; a0.w *= sc;
    a1.x *= sc; a1.y *= sc; a1.z *= sc; a1.w *= sc;
    vp4[lane] = a0; vp4[lane + 64] = a1;
}

// ---------- state finalize ----------
__global__ void k_state_final(const float* __restrict__ state_ws,
                              float* __restrict__ out) {
    int b = blockIdx.x;
    int tid = threadIdx.x;
    __shared__ float red[256];
    const float* sp = state_ws + (size_t)b * S;
    float m = -1e30f;
    for (int s = tid; s < S; s += 256) m = fmaxf(m, fabsf(sp[s]));
    red[tid] = m; __syncthreads();
    for (int off = 128; off > 0; off >>= 1) {
        if (tid < off) red[tid] = fmaxf(red[tid], red[tid + off]);
        __syncthreads();
    }
    m = red[0]; __syncthreads();
    float sum = 0.f;
    for (int s = tid; s < S; s += 256) sum += expf(fabsf(sp[s]) - m);
    red[tid] = sum; __syncthreads();
    for (int off = 128; off > 0; off >>= 1) {
        if (tid < off) red[tid] += red[tid + off];
        __syncthreads();
    }
    float inv = 1.0f / red[0];
    for (int s = tid; s < S; s += 256) {
        float v = sp[s];
        out[((size_t)b * S + s) * (D + 1)] = signf(v) * expf(fabsf(v) - m) * inv;
    }
}

// ---------- q / k projections -> bf16 hi/lo rows [B*S][R] ----------
__global__ void __launch_bounds__(256) k_qk2(const float* __restrict__ val1,
                                             const float* __restrict__ pair_a,
                                             const float* __restrict__ pair_b,
                                             __bf16* __restrict__ q_hi,
                                             __bf16* __restrict__ q_lo,
                                             __bf16* __restrict__ k_hi,
                                             __bf16* __restrict__ k_lo) {
    __shared__ __align__(16) float vrow[NR][D];
    __shared__ float redq[256];
    __shared__ float redk[256];
    int tid = threadIdx.x;
    int rowbase = blockIdx.x * NR;
    {
        const float4* gv = (const float4*)(val1 + (size_t)rowbase * D);
        float4* lv = (float4*)&vrow[0][0];
        for (int i = tid; i < NR * D / 4; i += 256) lv[i] = gv[i];
    }
    __syncthreads();
    int r = tid & 63, grp = tid >> 6;
    float accq[NR], acck[NR];
#pragma unroll
    for (int rr = 0; rr < NR; rr++) { accq[rr] = 0.f; acck[rr] = 0.f; }
    for (int d0 = grp * 128; d0 < grp * 128 + 128; d0 += 4) {
#pragma unroll
        for (int dd = 0; dd < 4; dd++) {
            float a  = pair_a[(size_t)(d0 + dd) * R + r];
            float bb = pair_b[(size_t)(d0 + dd) * R + r];
#pragma unroll
            for (int rr = 0; rr < NR; rr++) {
                float v = vrow[rr][d0 + dd];
                accq[rr] += v * a;
                acck[rr] += v * bb;
            }
        }
    }
    for (int rr = 0; rr < NR; rr++) {
        redq[tid] = accq[rr]; redk[tid] = acck[rr];
        __syncthreads();
        if (tid < 64) {
            float qv = redq[tid] + redq[tid + 64] + redq[tid + 128] + redq[tid + 192];
            float kv = redk[tid] + redk[tid + 64] + redk[tid + 128] + redk[tid + 192];
            __bf16 qh = (__bf16)qv, kh = (__bf16)kv;
            size_t o = (size_t)(rowbase + rr) * R + tid;
            q_hi[o] = qh; q_lo[o] = (__bf16)(qv - (float)qh);
            k_hi[o] = kh; k_lo[o] = (__bf16)(kv - (float)kh);
        }
        __syncthreads();
    }
}

// ---------- fused: p via split-bf16 MFMA -> f32 LDS halves -> topk -> eidx/ew ----------
__global__ void __launch_bounds__(256) k_pair2(const __bf16* __restrict__ q_hi,
                                               const __bf16* __restrict__ q_lo,
                                               const __bf16* __restrict__ k_hi,
                                               const __bf16* __restrict__ k_lo,
                                               int* __restrict__ eidx,
                                               float* __restrict__ ew_g) {
    __shared__ __align__(16) float sc[16 * 1024];   // 64 KB
    unsigned long long* candb = (unsigned long long*)sc;

    int lane = threadIdx.x & 63, wv = threadIdx.x >> 6;
    int mbase = blockIdx.x * 16;
    int b = mbase >> 11;
    int quad = lane >> 4, koff = quad << 3;
    size_t aoff = (size_t)(mbase + (lane & 15)) * R + koff;
    const bf16x8* ah = (const bf16x8*)(q_hi + aoff);
    const bf16x8* al = (const bf16x8*)(q_lo + aoff);
    bf16x8 a0h = ah[0], a1h = ah[4];
    bf16x8 a0l = al[0], a1l = al[4];
    int rl = quad << 2;
    int swz = quad << 3;
    size_t bbase = ((size_t)b << 11) * R;

    float4 v4[4][8];
    for (int half = 0; half < 2; half++) {
        for (int nt = 0; nt < 16; nt++) {
            int ncol = half * 1024 + wv * 256 + nt * 16 + (lane & 15);
            size_t boff = bbase + (size_t)ncol * R + koff;
            const bf16x8* bh = (const bf16x8*)(k_hi + boff);
            const bf16x8* bl = (const bf16x8*)(k_lo + boff);
            bf16x8 b0h = bh[0], b1h = bh[4];
            bf16x8 b0l = bl[0], b1l = bl[4];
            f32x4 c = {0.f, 0.f, 0.f, 0.f};
            c = __builtin_amdgcn_mfma_f32_16x16x32_bf16(a0h, b0h, c, 0, 0, 0);
            c = __builtin_amdgcn_mfma_f32_16x16x32_bf16(a1h, b1h, c, 0, 0, 0);
            c = __builtin_amdgcn_mfma_f32_16x16x32_bf16(a0h, b0l, c, 0, 0, 0);
            c = __builtin_amdgcn_mfma_f32_16x16x32_bf16(a1h, b1l, c, 0, 0, 0);
            c = __builtin_amdgcn_mfma_f32_16x16x32_bf16(a0l, b0h, c, 0, 0, 0);
            c = __builtin_amdgcn_mfma_f32_16x16x32_bf16(a1l, b1h, c, 0, 0, 0);
            int lcol = (ncol - half * 1024) ^ swz;
#pragma unroll
            for (int rg = 0; rg < 4; rg++)
                sc[(rl + rg) * 1024 + lcol] = c[rg];
        }
        __syncthreads();
#pragma unroll
        for (int rr = 0; rr < 4; rr++) {
            const float4* rp = (const float4*)(sc + (wv * 4 + rr) * 1024);
#pragma unroll
            for (int i = 0; i < 4; i++)
                v4[rr][half * 4 + i] = rp[(lane + 64 * i) ^ (wv << 1)];
        }
        __syncthreads();
    }

    for (int rr = 0; rr < 4; rr++) {
        int row = mbase + wv * 4 + rr;
        float myg; int myj;
        topk16_reg(v4[rr], candb + wv * 64, lane, myg, myj);

        float m = __shfl(fabsf(myg), 0);
        float e = (lane < KTOP) ? expf(fabsf(myg) - m) : 0.f;
        float esum = e;
#pragma unroll
        for (int off = 8; off > 0; off >>= 1) esum += __shfl_xor(esum, off, 64);
        esum = __shfl(esum, 0);
        float myw = signf(myg) * e / esum;

        if (lane < KTOP) {
            eidx[(size_t)row * KTOP + lane] = myj;
            ew_g[(size_t)row * KTOP + lane] = myw;
        }
    }
}

// ---------- mix: gather neighbors (4-wide), residual add, unit-norm, out ----------
__global__ void __launch_bounds__(256) k_mix(const int* __restrict__ eidx,
                                             const float* __restrict__ ew_g,
                                             const float* __restrict__ val1,
                                             float* __restrict__ out) {
    int lane = threadIdx.x & 63, wv = threadIdx.x >> 6;
    int row = blockIdx.x * 4 + wv;
    int b = row >> 11;

    int e_i = 0; float e_w = 0.f;
    if (lane < KTOP) {
        e_i = eidx[(size_t)row * KTOP + lane];
        e_w = ew_g[(size_t)row * KTOP + lane];
    }

    const float4* self4 = (const float4*)(val1 + (size_t)row * D);
    float4 a0 = self4[lane], a1 = self4[lane + 64];
    const float* vb = val1 + (((size_t)b * S) * D);
#pragma unroll
    for (int k0 = 0; k0 < KTOP; k0 += 4) {
        int ja[4]; float wa[4];
#pragma unroll
        for (int u = 0; u < 4; u++) {
            ja[u] = __shfl(e_i, k0 + u);
            wa[u] = __shfl(e_w, k0 + u);
        }
        float4 v0[4], v1[4];
#pragma unroll
        for (int u = 0; u < 4; u++) {
            const float4* nb4 = (const float4*)(vb + (size_t)ja[u] * D);
            v0[u] = nb4[lane]; v1[u] = nb4[lane + 64];
        }
#pragma unroll
        for (int u = 0; u < 4; u++) {
            float w = wa[u];
            a0.x += w * v0[u].x; a0.y += w * v0[u].y;
            a0.z += w * v0[u].z; a0.w += w * v0[u].w;
            a1.x += w * v1[u].x; a1.y += w * v1[u].y;
            a1.z += w * v1[u].z; a1.w += w * v1[u].w;
        }
    }
    float ss = a0.x * a0.x + a0.y * a0.y + a0.z * a0.z + a0.w * a0.w
             + a1.x * a1.x + a1.y * a1.y + a1.z * a1.z + a1.w * a1.w;
#pragma unroll
    for (int off = 32; off > 0; off >>= 1) ss += __shfl_xor(ss, off, 64);
    float sc = 1.0f / (sqrtf(ss) + 1e-6f);
    float* op = out + (size_t)row * (D + 1) + 1;
    int d0 = 4 * lane;
    op[d0 + 0] = a0.x * sc; op[d0 + 1] = a0.y * sc;
    op[d0 + 2] = a0.z * sc; op[d0 + 3] = a0.w * sc;
    op[256 + d0 + 0] = a1.x * sc; op[256 + d0 + 1] = a1.y * sc;
    op[256 + d0 + 2] = a1.z * sc; op[256 + d0 + 3] = a1.w * sc;
}

extern "C" void kernel_launch(void* const* d_in, const int* in_sizes, int n_in,
                              void* d_out, int out_size, void* d_ws, size_t ws_size,
                              hipStream_t stream) {
    (void)in_sizes; (void)n_in; (void)out_size; (void)ws_size;
    const float* x          = (const float*)d_in[0];
    const float* init_state = (const float*)d_in[1];
    const float* init_val   = (const float*)d_in[2];
    const float* route_a    = (const float*)d_in[3];
    const float* route_b    = (const float*)d_in[4];
    const float* pair_a     = (const float*)d_in[5];
    const float* pair_b     = (const float*)d_in[6];
    float* out = (float*)d_out;

    float* ws       = (float*)d_ws;
    float* val1     = ws;                               // B*S*D f32
    float* state_ws = val1 + (size_t)B * S * D;         // B*S
    float* coef     = state_ws + (size_t)B * S;         // B*T*K
    float* xinv_g   = coef + (size_t)B * T * KTOP;      // B*T
    int*   bincount = (int*)(xinv_g + (size_t)B * T);   // B*S
    int*   binlist  = bincount + (size_t)B * S;         // B*S*CAP
    int*   eidx     = binlist;                          // reuse (dead after accum)
    float* ew       = (float*)(binlist + (size_t)B * S * KTOP);
    __bf16* xr_hi   = (__bf16*)(binlist + (size_t)B * S * CAP);  // B*T*R
    __bf16* xr_lo   = xr_hi + (size_t)B * T * R;
    __bf16* rbT_hi  = xr_lo + (size_t)B * T * R;        // S*R
    __bf16* rbT_lo  = rbT_hi + (size_t)S * R;
    __bf16* q_hi    = rbT_lo + (size_t)S * R;           // B*S*R
    __bf16* q_lo    = q_hi + (size_t)B * S * R;
    __bf16* k_hi    = q_lo + (size_t)B * S * R;
    __bf16* k_lo    = k_hi + (size_t)B * S * R;

    hipMemsetAsync(bincount, 0, (size_t)B * S * sizeof(int), stream);
    hipLaunchKernelGGL(k_init_state, dim3(B), dim3(256), 0, stream, init_state, state_ws);
    hipLaunchKernelGGL(k_bcast, dim3(B * S / 4), dim3(256), 0, stream, init_val, val1);
    hipLaunchKernelGGL(k_prep, dim3(S / 64), dim3(256), 0, stream, route_b, rbT_hi, rbT_lo);
    hipLaunchKernelGGL(k_xr, dim3(B * T / NT), dim3(256), 0, stream,
                       x, route_a, xr_hi, xr_lo, xinv_g);
    hipLaunchKernelGGL(k_score2, dim3(B * T / 16), dim3(256), 0, stream,
                       xr_hi, xr_lo, rbT_hi, rbT_lo, xinv_g, x, val1, state_ws,
                       coef, bincount, binlist);
    hipLaunchKernelGGL(k_state_final, dim3(B), dim3(256), 0, stream, state_ws, out);
    hipLaunchKernelGGL(k_accum, dim3(B * S / 4), dim3(256), 0, stream,
                       x, coef, bincount, binlist, val1);
    hipLaunchKernelGGL(k_qk2, dim3(B * S / NR), dim3(256), 0, stream,
                       val1, pair_a, pair_b, q_hi, q_lo, k_hi, k_lo);
    hipLaunchKernelGGL(k_pair2, dim3(B * S / 16), dim3(256), 0, stream,
                       q_hi, q_lo, k_hi, k_lo, eidx, ew);
    hipLaunchKernelGGL(k_mix, dim3(B * S / 4), dim3(256), 0, stream,
                       eidx, ew, val1, out);
}